// Round 8
// baseline (5833.676 us; speedup 1.0000x reference)
//
#include <hip/hip_runtime.h>
#include <stdint.h>
#include <string.h>

// Problem dims (fixed by the reference)
#define BDIM   4096
#define INDIM  1024
#define XDIM   2048
#define OUTDIM 512
#define MCH    (BDIM / 16)   // 256 row-chunks along M for packed activations

#define LO_SCALE 2048.0f         // 2^11: lifts fp16 lo-plane out of subnormals
#define INV_LO_SCALE (1.0f / 2048.0f)

typedef _Float16 f16x8 __attribute__((ext_vector_type(8)));
typedef float f32x4 __attribute__((ext_vector_type(4)));
typedef unsigned short u16x8 __attribute__((ext_vector_type(8)));
typedef unsigned short u16x4 __attribute__((ext_vector_type(4)));

__device__ __forceinline__ unsigned short h2u(_Float16 h) {
  unsigned short u;
  memcpy(&u, &h, 2);
  return u;
}

// split f32 into hi fp16 + scaled-lo fp16 (combined ~22 mantissa bits)
__device__ __forceinline__ void split_h(float v, unsigned short& h,
                                        unsigned short& l) {
  _Float16 hh = (_Float16)v;                       // RTNE
  float r = v - (float)hh;                         // exact
  _Float16 ll = (_Float16)(r * LO_SCALE);          // |r|*2^11 <= |v|, no inf
  h = h2u(hh);
  l = h2u(ll);
}

// async global->LDS, 16B per lane; LDS dest wave-uniform base + lane*16
__device__ __forceinline__ void gld_lds16(const void* g, void* l) {
  __builtin_amdgcn_global_load_lds(
      (const __attribute__((address_space(1))) uint32_t*)g,
      (__attribute__((address_space(3))) uint32_t*)l, 16, 0, 0);
}

// fused RandomActivation + clip (relu/sigmoid/tanh/leaky(.1)/selu), libm-grade
__device__ __forceinline__ float rand_act(float v, int a, float mo) {
  float r;
  if (a == 0) {
    r = fmaxf(v, 0.0f);
  } else if (a == 1) {
    r = 1.0f / (1.0f + expf(-v));
  } else if (a == 2) {
    r = tanhf(v);
  } else if (a == 3) {
    r = (v >= 0.0f) ? v : 0.1f * v;
  } else {  // selu (matches jax: scale * where(v>0, v, alpha*expm1(v)))
    r = (v > 0.0f) ? 1.0507009873554805f * v
                   : 1.7580993408473766f * expm1f(v);
  }
  return fminf(r, mo);
}

// ---------------------------------------------------------------------------
// PACKED LAYOUT: tensor X[rows][K] is stored as
//   packed[k/32][row/16][lane(64)][8 halfs],
// lane = quad*16 + m16 holding X[chunkrow*16 + m16][kstep*32 + quad*8 + j].
// Each (kstep,chunk) = contiguous 1 KB: staging DMA is consecutive-lane-
// contiguous AND compute ds_read_b128 is contiguous (zero conflicts).
// Concat along K = packed tensors back-to-back.
// ---------------------------------------------------------------------------

// x[BDIM][Kin] f32 row-major -> packed hi/lo planes. grid(Kin/32, BDIM/64)x256
__global__ void pack_x(const float* __restrict__ s,
                       unsigned short* __restrict__ dh,
                       unsigned short* __restrict__ dl, int Kin) {
  int ks = blockIdx.x;
  int mblk = blockIdx.y;
  int cc = threadIdx.x >> 6;        // chunk within 64-row group
  int lane = threadIdx.x & 63;
  int m16 = lane & 15, quad = lane >> 4;
  int row = mblk * 64 + cc * 16 + m16;
  const float* src = s + (size_t)row * Kin + ks * 32 + quad * 8;
  size_t o = ((size_t)ks * MCH + mblk * 4 + cc) * 512 + lane * 8;
  float4 v0 = *(const float4*)src;
  float4 v1 = *(const float4*)(src + 4);
  float vs[8] = {v0.x, v0.y, v0.z, v0.w, v1.x, v1.y, v1.z, v1.w};
  u16x8 vh, vl;
#pragma unroll
  for (int j = 0; j < 8; j++) {
    unsigned short h, l;
    split_h(vs[j], h, l);
    vh[j] = h;
    vl[j] = l;
  }
  *(u16x8*)(dh + o) = vh;
  *(u16x8*)(dl + o) = vl;
}

// W[K][N] f32 row-major -> packed-BT hi/lo (rows=N, Kdim=K).
// grid(N/32, K/32), block(32,8).
__global__ void pack_w(const float* __restrict__ W,
                       unsigned short* __restrict__ dh,
                       unsigned short* __restrict__ dl, int K, int N) {
  __shared__ float t[32][33];       // t[k'][n']
  int n0 = blockIdx.x * 32, k0 = blockIdx.y * 32;
  int tx = threadIdx.x, ty = threadIdx.y;
#pragma unroll
  for (int i = 0; i < 32; i += 8)
    t[ty + i][tx] = W[(size_t)(k0 + ty + i) * N + n0 + tx];
  __syncthreads();
  int tt = ty * 32 + tx;            // 0..255
  int ci = tt >> 7;                 // n-chunk 0/1
  int rem = tt & 127;
  int lane = rem >> 1;
  int j4 = (rem & 1) * 4;
  int m16 = lane & 15, quad = lane >> 4;
  size_t o = ((size_t)(k0 >> 5) * (N >> 4) + (n0 >> 4) + ci) * 512 +
             lane * 8 + j4;
  u16x4 vh, vl;
#pragma unroll
  for (int jj = 0; jj < 4; jj++) {
    float v = t[quad * 8 + j4 + jj][ci * 16 + m16];
    unsigned short h, l;
    split_h(v, h, l);
    vh[jj] = h;
    vl[jj] = l;
  }
  *(u16x4*)(dh + o) = vh;
  *(u16x4*)(dl + o) = vl;
}

// C[M,N] = act( A[M,K] @ BT[N,K]^T + bias ), split-fp16 (3-term) precision.
// acc1 = hi*hi; acc2 = hi*lo' + lo'*hi at scale 2^11. Final = acc1+acc2/2^11.
//
// Round-17 = Round-7 (best verified: 194.5 us hot, 1116 us total) + intra-
// window PARITY SKEW:
//  - Even waves per K-sub-step: [aH reads; hh x8NT, hl x8NT? -> actually
//    8NT+ ... ; aL reads; lh]. Odd waves: [aL reads; lh; aH reads; hh, hl].
//    All orders consume only already-resident B regs -> no ledger change.
//    Effect: half the waves MFMA while the other half issue LDS reads
//    (T5-precondition role diversity; setprio now has something to
//    arbitrate). acc2's hl/lh accumulation order swaps on odd waves —
//    tolerance-level change only.
//  - Everything else (NT template, counted-vmcnt single-barrier window,
//    ledger, staging, linear block order, 64-arch-VGPR budget) unchanged.
template <bool OUT_F16, int NT>
__global__ __launch_bounds__(256, 4) void gemm_split_act(
    const short* __restrict__ A1h, const short* __restrict__ A1l,
    const short* __restrict__ A2h, const short* __restrict__ A2l,
    const short* __restrict__ BTh, const short* __restrict__ BTl,
    const float* __restrict__ bias, const float* __restrict__ mo,
    const int* __restrict__ aid, unsigned short* __restrict__ Ch,
    unsigned short* __restrict__ Cl, float* __restrict__ Cf, int N, int K,
    int Ksplit) {
  __shared__ short lds0[2 * 8 * 512];   // 16 KB: [sub][8 chunks][512]
  __shared__ short lds1[2 * 8 * 512];   // chunks 0-3 hi rows 0-63, 4-7 lo

  const int tid = threadIdx.x;
  const int lane = tid & 63;
  const int wave = tid >> 6;        // 0..3 = n-strip of wave
  const int m16 = lane & 15, quad = lane >> 4;
  const bool odd = (wave & 1) != 0;

  const int blockN = blockIdx.x * (NT * 64);  // linear order (proven)
  const int blockM = blockIdx.y * 64;

  f32x4 acc1[4][NT];  // hi*hi
  f32x4 acc2[4][NT];  // (hi*lo' + lo'*hi), scale 2^11
#pragma unroll
  for (int i = 0; i < 4; i++)
#pragma unroll
    for (int j = 0; j < NT; j++) {
      acc1[i][j] = (f32x4){0.f, 0.f, 0.f, 0.f};
      acc2[i][j] = (f32x4){0.f, 0.f, 0.f, 0.f};
    }

  const int KSTEPS = K >> 5;        // 32/64/128 — always even, >= 32
  const int W = KSTEPS >> 1;        // windows (16/32/64)
  const int KS1W = (Ksplit >> 5) >> 1;  // part-1 windows (even splits only)

  // ---- staging: one window = 2 k-steps = 4 DMAs/wave (1 KB each)
  const short* sAh = A1h;
  const short* sAl = A1l;
  const unsigned aBase0 = (unsigned)((blockM >> 4) * 512 + lane * 8);
  unsigned aOff = aBase0;
  int stageW = 0;
  auto stageNext = [&](short* dst) {
#pragma unroll
    for (int sub = 0; sub < 2; sub++) {
#pragma unroll
      for (int s = 0; s < 2; s++) {
        int g = wave * 2 + s;          // 0..7
        const short* plane = (g < 4) ? sAh : sAl;
        gld_lds16(plane + aOff + sub * (MCH * 512) + (g & 3) * 512,
                  dst + sub * 4096 + g * 512);
      }
    }
    aOff += 2u * (MCH * 512);
    if (++stageW == KS1W) { sAh = A2h; sAl = A2l; aOff = aBase0; }
  };

  // ---- B-load state (2*NT x 16B loads per wave per K-step), 32-bit offset
  unsigned bOff = (unsigned)(((blockN >> 4) + wave * NT) * 512 + lane * 8);
  const unsigned bStride = (unsigned)N * 32;
  auto loadBNext = [&](f16x8 (&bH)[NT], f16x8 (&bL)[NT]) {
#pragma unroll
    for (int t = 0; t < NT; t++) {
      bH[t] = *(const f16x8*)(BTh + bOff + t * 512);
      bL[t] = *(const f16x8*)(BTl + bOff + t * 512);
    }
    bOff += bStride;
  };

  f16x8 aH[4], aL[4];               // single A-frag set
  f16x8 b0H[NT], b0L[NT], b1H[NT], b1L[NT];

  // cluster pieces (each consumes only resident B regs)
  auto readAH = [&](const short* buf, int sub) {
#pragma unroll
    for (int t = 0; t < 4; t++)
      aH[t] = *(const f16x8*)&buf[sub * 4096 + t * 512 + lane * 8];
  };
  auto readAL = [&](const short* buf, int sub) {
#pragma unroll
    for (int t = 0; t < 4; t++)
      aL[t] = *(const f16x8*)&buf[sub * 4096 + (4 + t) * 512 + lane * 8];
  };
  auto mfmaHH_HL = [&](f16x8 (&bH)[NT], f16x8 (&bL)[NT]) {
    __builtin_amdgcn_s_setprio(1);
#pragma unroll
    for (int i = 0; i < 4; i++)
#pragma unroll
      for (int j = 0; j < NT; j++)
        acc1[i][j] = __builtin_amdgcn_mfma_f32_16x16x32_f16(aH[i], bH[j],
                                                            acc1[i][j], 0, 0, 0);
#pragma unroll
    for (int i = 0; i < 4; i++)
#pragma unroll
      for (int j = 0; j < NT; j++)
        acc2[i][j] = __builtin_amdgcn_mfma_f32_16x16x32_f16(aH[i], bL[j],
                                                            acc2[i][j], 0, 0, 0);
    __builtin_amdgcn_s_setprio(0);
  };
  auto mfmaLH = [&](f16x8 (&bH)[NT]) {
    __builtin_amdgcn_s_setprio(1);
#pragma unroll
    for (int i = 0; i < 4; i++)
#pragma unroll
      for (int j = 0; j < NT; j++)
        acc2[i][j] = __builtin_amdgcn_mfma_f32_16x16x32_f16(aL[i], bH[j],
                                                            acc2[i][j], 0, 0, 0);
    __builtin_amdgcn_s_setprio(0);
  };

  // parity-skewed K-sub-step: evens lead with the 16-MFMA aH cluster while
  // odds lead with the 8-MFMA aL cluster -> LDS-read bursts of one parity
  // overlap MFMA clusters of the other.
  auto computeSub = [&](const short* buf, int sub, f16x8 (&bH)[NT],
                        f16x8 (&bL)[NT]) {
    if (!odd) {
      readAH(buf, sub);
      mfmaHH_HL(bH, bL);
      readAL(buf, sub);
      mfmaLH(bH);
    } else {
      readAL(buf, sub);
      mfmaLH(bH);
      readAH(buf, sub);
      mfmaHH_HL(bH, bL);
    }
  };

#define SB0 __builtin_amdgcn_sched_barrier(0)
#define WAIT_STAGE()                                              \
  do {                                                            \
    if constexpr (NT == 2)                                        \
      asm volatile("s_waitcnt vmcnt(4)" ::: "memory");            \
    else                                                          \
      asm volatile("s_waitcnt vmcnt(2)" ::: "memory");            \
  } while (0)

  // ---- prologue: stage window 0 -> lds0; load B(0); publish lds0.
  stageNext(lds0);                   // S0: 4  (FIFO-oldest)
  loadBNext(b0H, b0L);               // L(k0): 2NT
  WAIT_STAGE();                      // retires S0; L(k0) stays in flight
  __builtin_amdgcn_s_barrier();
  SB0;
  // invariant entering window w: outstanding [L(k0) 2NT]; buf[w] published

  short* cur = lds0;
  short* oth = lds1;
  for (int w = 0; w < W - 1; ++w) {
    loadBNext(b1H, b1L);             // L(k1): 2NT
    stageNext(oth);                  // S(w+1): 4 (other buffer; its reads
                                     // retired before last barrier)
    computeSub(cur, 0, b0H, b0L);    // auto-wait retires L(k0)
    SB0;                             // pin: S issued before L(k2)
    loadBNext(b0H, b0L);             // L(k2): 2NT
    computeSub(cur, 1, b1H, b1L);    // auto-wait retires L(k1)
    SB0;
    WAIT_STAGE();                    // retires S(w+1); L(k2) crosses
    __builtin_amdgcn_s_barrier();    // publish buf[w+1]
    SB0;
    short* t = cur; cur = oth; oth = t;
  }

  // ---- tail window W-1: no stage, no L(k2); compiler auto-waits.
  loadBNext(b1H, b1L);
  computeSub(cur, 0, b0H, b0L);
  computeSub(cur, 1, b1H, b1L);

  // epilogue: combine accs, bias + per-column activation + clip.
  // C/D map col=lane&15, row=quad*4+reg (m89-verified).
  // OUT_F16 path writes PACKED layout (next layer's A): chunkrow=row>>4,
  // kstep=col>>5, lane'=((col>>3)&3)*16 + (row&15), j'=col&7.
#pragma unroll
  for (int j = 0; j < NT; j++) {
    int col = blockN + wave * (NT * 16) + j * 16 + m16;
    float b = bias[col];
    float m = mo[col];
    int a = aid[col];
    size_t kbase = OUT_F16 ? ((size_t)(col >> 5) * MCH) * 512 +
                                 (size_t)((col >> 3) & 3) * 128 + (col & 7)
                           : 0;
#pragma unroll
    for (int i = 0; i < 4; i++) {
#pragma unroll
      for (int r = 0; r < 4; r++) {
        int row = blockM + i * 16 + quad * 4 + r;
        float s = acc1[i][j][r] + acc2[i][j][r] * INV_LO_SCALE;
        float v = rand_act(s + b, a, m);
        if (OUT_F16) {
          unsigned short h, l;
          split_h(v, h, l);
          size_t pidx = kbase + (size_t)(row >> 4) * 512 + (row & 15) * 8;
          Ch[pidx] = h;
          Cl[pidx] = l;
        } else {
          Cf[(size_t)row * N + col] = v;
        }
      }
    }
  }
}

extern "C" void kernel_launch(void* const* d_in, const int* in_sizes, int n_in,
                              void* d_out, int out_size, void* d_ws,
                              size_t ws_size, hipStream_t stream) {
  (void)in_sizes; (void)n_in; (void)out_size; (void)ws_size;

  const float* x     = (const float*)d_in[0];
  const float* W_in  = (const float*)d_in[1];
  const float* b_in  = (const float*)d_in[2];
  const float* Wh[6] = {(const float*)d_in[3], (const float*)d_in[4],
                        (const float*)d_in[5], (const float*)d_in[6],
                        (const float*)d_in[7], (const float*)d_in[8]};
  const float* bh    = (const float*)d_in[9];
  const float* W_out = (const float*)d_in[10];
  const float* b_out = (const float*)d_in[11];
  const float* mo_in = (const float*)d_in[12];
  const float* mo_h  = (const float*)d_in[13];
  const float* mo_out= (const float*)d_in[14];
  const int* aid_in  = (const int*)d_in[15];
  const int* aid_h   = (const int*)d_in[16];
  const int* aid_out = (const int*)d_in[17];

  const int hin[6] = {XDIM, XDIM, 2 * XDIM, XDIM, 2 * XDIM, XDIM};

  // workspace layout (~264 MB); each tensor = hi plane then lo plane (packed)
  char* p = (char*)d_ws;
  auto take = [&](size_t elems) {
    short* q = (short*)p;
    p += elems * 2 * 2;  // hi + lo, 2B each
    return q;
  };
  short* x_s = take((size_t)BDIM * INDIM);
  size_t xpl = (size_t)BDIM * INDIM;
  short* w_in_s = take((size_t)XDIM * INDIM);
  size_t wpl_in = (size_t)XDIM * INDIM;
  short* w_h_s[6];
  size_t wpl_h[6];
  for (int i = 0; i < 6; i++) {
    wpl_h[i] = (size_t)XDIM * hin[i];
    w_h_s[i] = take(wpl_h[i]);
  }
  short* w_out_s = take((size_t)OUTDIM * XDIM);
  size_t wpl_out = (size_t)OUTDIM * XDIM;
  const size_t apl = (size_t)BDIM * XDIM;  // activation plane
  short* actA = take(apl);
  short* actB = take(apl);
  short* actC = take(apl);

  // 1) pack x -> hi/lo fp16 packed
  pack_x<<<dim3(INDIM / 32, BDIM / 64), dim3(256), 0, stream>>>(
      x, (unsigned short*)x_s, (unsigned short*)(x_s + xpl), INDIM);
  // 2) pack all weights: W(K,N) -> packed BT(rows=N, Kdim=K) hi/lo
  pack_w<<<dim3(XDIM / 32, INDIM / 32), dim3(32, 8), 0, stream>>>(
      W_in, (unsigned short*)w_in_s, (unsigned short*)(w_in_s + wpl_in), INDIM,
      XDIM);
  for (int i = 0; i < 6; i++)
    pack_w<<<dim3(XDIM / 32, hin[i] / 32), dim3(32, 8), 0, stream>>>(
        Wh[i], (unsigned short*)w_h_s[i],
        (unsigned short*)(w_h_s[i] + wpl_h[i]), hin[i], XDIM);
  pack_w<<<dim3(OUTDIM / 32, XDIM / 32), dim3(32, 8), 0, stream>>>(
      W_out, (unsigned short*)w_out_s, (unsigned short*)(w_out_s + wpl_out),
      XDIM, OUTDIM);

  // 3) GEMM chain with 3 rotating activation buffers (all NT=2, N=2048)
  auto G = [&](const short* A1, size_t a1pl, const short* A2, size_t a2pl,
               const short* W, size_t wpl, const float* bi, const float* m,
               const int* a, short* Cb, int K, int Ks) {
    dim3 grid(XDIM / 128, BDIM / 64);
    const short* A2h = A2;
    const short* A2l = A2 ? A2 + a2pl : nullptr;
    gemm_split_act<true, 2><<<grid, 256, 0, stream>>>(
        A1, A1 + a1pl, A2h, A2l, W, W + wpl, bi, m, a, (unsigned short*)Cb,
        (unsigned short*)(Cb + apl), nullptr, XDIM, K, Ks);
  };

  // input layer: outs[0]=actA
  G(x_s, xpl, nullptr, 0, w_in_s, wpl_in, b_in, mo_in, aid_in, actA,
    INDIM, INDIM);
  // L0: outs[1]=actB
  G(actA, apl, nullptr, 0, w_h_s[0], wpl_h[0], bh + 0 * XDIM, mo_h + 0 * XDIM,
    aid_h + 0 * XDIM, actB, XDIM, XDIM);
  // L1: outs[2]=actC
  G(actB, apl, nullptr, 0, w_h_s[1], wpl_h[1], bh + 1 * XDIM, mo_h + 1 * XDIM,
    aid_h + 1 * XDIM, actC, XDIM, XDIM);
  // L2 (concat outs2,outs1): outs[3]=actA
  G(actC, apl, actB, apl, w_h_s[2], wpl_h[2], bh + 2 * XDIM, mo_h + 2 * XDIM,
    aid_h + 2 * XDIM, actA, 2 * XDIM, XDIM);
  // L3: outs[4]=actB
  G(actA, apl, nullptr, 0, w_h_s[3], wpl_h[3], bh + 3 * XDIM, mo_h + 3 * XDIM,
    aid_h + 3 * XDIM, actB, XDIM, XDIM);
  // L4 (concat outs4,outs3): outs[5]=actC
  G(actB, apl, actA, apl, w_h_s[4], wpl_h[4], bh + 4 * XDIM, mo_h + 4 * XDIM,
    aid_h + 4 * XDIM, actC, 2 * XDIM, XDIM);
  // L5: outs[6]=actB
  G(actC, apl, nullptr, 0, w_h_s[5], wpl_h[5], bh + 5 * XDIM, mo_h + 5 * XDIM,
    aid_h + 5 * XDIM, actB, XDIM, XDIM);
  // output layer -> d_out (fp32, row-major): N=512 -> NT=1, 64-wide tiles,
  // grid (8,64)=512 blocks = 2 blocks/CU.
  {
    dim3 grid(OUTDIM / 64, BDIM / 64);
    gemm_split_act<false, 1><<<grid, 256, 0, stream>>>(
        actB, actB + apl, nullptr, nullptr, w_out_s, w_out_s + wpl_out, b_out,
        mo_out, aid_out, nullptr, nullptr, (float*)d_out, OUTDIM, XDIM, XDIM);
  }
}

// Round 9
// 1088.074 us; speedup vs baseline: 5.3615x; 5.3615x over previous
//
#include <hip/hip_runtime.h>
#include <stdint.h>
#include <string.h>

// Problem dims (fixed by the reference)
#define BDIM   4096
#define INDIM  1024
#define XDIM   2048
#define OUTDIM 512
#define MCH    (BDIM / 16)   // 256 row-chunks along M for packed activations

#define LO_SCALE 2048.0f         // 2^11: lifts fp16 lo-plane out of subnormals
#define INV_LO_SCALE (1.0f / 2048.0f)

typedef _Float16 f16x8 __attribute__((ext_vector_type(8)));
typedef float f32x4 __attribute__((ext_vector_type(4)));
typedef unsigned short u16x8 __attribute__((ext_vector_type(8)));
typedef unsigned short u16x4 __attribute__((ext_vector_type(4)));

__device__ __forceinline__ unsigned short h2u(_Float16 h) {
  unsigned short u;
  memcpy(&u, &h, 2);
  return u;
}

// split f32 into hi fp16 + scaled-lo fp16 (combined ~22 mantissa bits)
__device__ __forceinline__ void split_h(float v, unsigned short& h,
                                        unsigned short& l) {
  _Float16 hh = (_Float16)v;                       // RTNE
  float r = v - (float)hh;                         // exact
  _Float16 ll = (_Float16)(r * LO_SCALE);          // |r|*2^11 <= |v|, no inf
  h = h2u(hh);
  l = h2u(ll);
}

// async global->LDS, 16B per lane; LDS dest wave-uniform base + lane*16
__device__ __forceinline__ void gld_lds16(const void* g, void* l) {
  __builtin_amdgcn_global_load_lds(
      (const __attribute__((address_space(1))) uint32_t*)g,
      (__attribute__((address_space(3))) uint32_t*)l, 16, 0, 0);
}

// fused RandomActivation + clip (relu/sigmoid/tanh/leaky(.1)/selu), libm-grade
__device__ __forceinline__ float rand_act(float v, int a, float mo) {
  float r;
  if (a == 0) {
    r = fmaxf(v, 0.0f);
  } else if (a == 1) {
    r = 1.0f / (1.0f + expf(-v));
  } else if (a == 2) {
    r = tanhf(v);
  } else if (a == 3) {
    r = (v >= 0.0f) ? v : 0.1f * v;
  } else {  // selu (matches jax: scale * where(v>0, v, alpha*expm1(v)))
    r = (v > 0.0f) ? 1.0507009873554805f * v
                   : 1.7580993408473766f * expm1f(v);
  }
  return fminf(r, mo);
}

// ---------------------------------------------------------------------------
// PACKED LAYOUT: tensor X[rows][K] is stored as
//   packed[k/32][row/16][lane(64)][8 halfs],
// lane = quad*16 + m16 holding X[chunkrow*16 + m16][kstep*32 + quad*8 + j].
// Each (kstep,chunk) = contiguous 1 KB: staging DMA is consecutive-lane-
// contiguous AND compute ds_read_b128 is contiguous (zero conflicts).
// Concat along K = packed tensors back-to-back.
// ---------------------------------------------------------------------------

// x[BDIM][Kin] f32 row-major -> packed hi/lo planes. grid(Kin/32, BDIM/64)x256
__global__ void pack_x(const float* __restrict__ s,
                       unsigned short* __restrict__ dh,
                       unsigned short* __restrict__ dl, int Kin) {
  int ks = blockIdx.x;
  int mblk = blockIdx.y;
  int cc = threadIdx.x >> 6;        // chunk within 64-row group
  int lane = threadIdx.x & 63;
  int m16 = lane & 15, quad = lane >> 4;
  int row = mblk * 64 + cc * 16 + m16;
  const float* src = s + (size_t)row * Kin + ks * 32 + quad * 8;
  size_t o = ((size_t)ks * MCH + mblk * 4 + cc) * 512 + lane * 8;
  float4 v0 = *(const float4*)src;
  float4 v1 = *(const float4*)(src + 4);
  float vs[8] = {v0.x, v0.y, v0.z, v0.w, v1.x, v1.y, v1.z, v1.w};
  u16x8 vh, vl;
#pragma unroll
  for (int j = 0; j < 8; j++) {
    unsigned short h, l;
    split_h(vs[j], h, l);
    vh[j] = h;
    vl[j] = l;
  }
  *(u16x8*)(dh + o) = vh;
  *(u16x8*)(dl + o) = vl;
}

// W[K][N] f32 row-major -> packed-BT hi/lo (rows=N, Kdim=K).
// grid(N/32, K/32), block(32,8).
__global__ void pack_w(const float* __restrict__ W,
                       unsigned short* __restrict__ dh,
                       unsigned short* __restrict__ dl, int K, int N) {
  __shared__ float t[32][33];       // t[k'][n']
  int n0 = blockIdx.x * 32, k0 = blockIdx.y * 32;
  int tx = threadIdx.x, ty = threadIdx.y;
#pragma unroll
  for (int i = 0; i < 32; i += 8)
    t[ty + i][tx] = W[(size_t)(k0 + ty + i) * N + n0 + tx];
  __syncthreads();
  int tt = ty * 32 + tx;            // 0..255
  int ci = tt >> 7;                 // n-chunk 0/1
  int rem = tt & 127;
  int lane = rem >> 1;
  int j4 = (rem & 1) * 4;
  int m16 = lane & 15, quad = lane >> 4;
  size_t o = ((size_t)(k0 >> 5) * (N >> 4) + (n0 >> 4) + ci) * 512 +
             lane * 8 + j4;
  u16x4 vh, vl;
#pragma unroll
  for (int jj = 0; jj < 4; jj++) {
    float v = t[quad * 8 + j4 + jj][ci * 16 + m16];
    unsigned short h, l;
    split_h(v, h, l);
    vh[jj] = h;
    vl[jj] = l;
  }
  *(u16x4*)(dh + o) = vh;
  *(u16x4*)(dl + o) = vl;
}

// C[M,N] = act( A[M,K] @ BT[N,K]^T + bias ), split-fp16 (3-term) precision.
// acc1 = hi*hi; acc2 = hi*lo' + lo'*hi at scale 2^11. Final = acc1+acc2/2^11.
//
// Round-18 = Round-7 verbatim (best verified: 194.5 us hot, 1116 us total).
// R8's parity skew is REVERTED: its if/else around the cluster lambdas put
// aH/aL across a control-flow merge -> SROA defeated -> f16x8 arrays went
// to scratch (WRITE_SIZE 35MB->3.4GB, MfmaUtil 46->6.5). Session box:
//  - 4 waves/SIMD mandatory (R2/R4) -> arch VGPR <= 64 with 64-AGPR acc.
//  - 16x16x32 MFMA beats 32x32x16 at this wave count (R6).
//  - counted-vmcnt single-barrier window; ledger never drains to 0.
//  - linear block order (R1: swizzle +70% FETCH).
//  - NT template: NT=2 for N=2048 layers, NT=1 for the N=512 output layer.
template <bool OUT_F16, int NT>
__global__ __launch_bounds__(256, 4) void gemm_split_act(
    const short* __restrict__ A1h, const short* __restrict__ A1l,
    const short* __restrict__ A2h, const short* __restrict__ A2l,
    const short* __restrict__ BTh, const short* __restrict__ BTl,
    const float* __restrict__ bias, const float* __restrict__ mo,
    const int* __restrict__ aid, unsigned short* __restrict__ Ch,
    unsigned short* __restrict__ Cl, float* __restrict__ Cf, int N, int K,
    int Ksplit) {
  __shared__ short lds0[2 * 8 * 512];   // 16 KB: [sub][8 chunks][512]
  __shared__ short lds1[2 * 8 * 512];   // chunks 0-3 hi rows 0-63, 4-7 lo

  const int tid = threadIdx.x;
  const int lane = tid & 63;
  const int wave = tid >> 6;        // 0..3 = n-strip of wave
  const int m16 = lane & 15, quad = lane >> 4;

  const int blockN = blockIdx.x * (NT * 64);  // linear order (proven)
  const int blockM = blockIdx.y * 64;

  f32x4 acc1[4][NT];  // hi*hi
  f32x4 acc2[4][NT];  // (hi*lo' + lo'*hi), scale 2^11
#pragma unroll
  for (int i = 0; i < 4; i++)
#pragma unroll
    for (int j = 0; j < NT; j++) {
      acc1[i][j] = (f32x4){0.f, 0.f, 0.f, 0.f};
      acc2[i][j] = (f32x4){0.f, 0.f, 0.f, 0.f};
    }

  const int KSTEPS = K >> 5;        // 32/64/128 — always even, >= 32
  const int W = KSTEPS >> 1;        // windows (16/32/64)
  const int KS1W = (Ksplit >> 5) >> 1;  // part-1 windows (even splits only)

  // ---- staging: one window = 2 k-steps = 4 DMAs/wave (1 KB each)
  const short* sAh = A1h;
  const short* sAl = A1l;
  const unsigned aBase0 = (unsigned)((blockM >> 4) * 512 + lane * 8);
  unsigned aOff = aBase0;
  int stageW = 0;
  auto stageNext = [&](short* dst) {
#pragma unroll
    for (int sub = 0; sub < 2; sub++) {
#pragma unroll
      for (int s = 0; s < 2; s++) {
        int g = wave * 2 + s;          // 0..7
        const short* plane = (g < 4) ? sAh : sAl;
        gld_lds16(plane + aOff + sub * (MCH * 512) + (g & 3) * 512,
                  dst + sub * 4096 + g * 512);
      }
    }
    aOff += 2u * (MCH * 512);
    if (++stageW == KS1W) { sAh = A2h; sAl = A2l; aOff = aBase0; }
  };

  // ---- B-load state (2*NT x 16B loads per wave per K-step), 32-bit offset
  unsigned bOff = (unsigned)(((blockN >> 4) + wave * NT) * 512 + lane * 8);
  const unsigned bStride = (unsigned)N * 32;
  auto loadBNext = [&](f16x8 (&bH)[NT], f16x8 (&bL)[NT]) {
#pragma unroll
    for (int t = 0; t < NT; t++) {
      bH[t] = *(const f16x8*)(BTh + bOff + t * 512);
      bL[t] = *(const f16x8*)(BTl + bOff + t * 512);
    }
    bOff += bStride;
  };

  f16x8 aH[4], aL[4];               // single A-frag set
  f16x8 b0H[NT], b0L[NT], b1H[NT], b1L[NT];

  // one K-sub-step: aH reads -> 8NT MFMA -> aL reads -> 4NT MFMA (staggered
  // liveness keeps arch VGPR <= 64)
  auto computeSub = [&](const short* buf, int sub, f16x8 (&bH)[NT],
                        f16x8 (&bL)[NT]) {
#pragma unroll
    for (int t = 0; t < 4; t++)
      aH[t] = *(const f16x8*)&buf[sub * 4096 + t * 512 + lane * 8];
    __builtin_amdgcn_s_setprio(1);
#pragma unroll
    for (int i = 0; i < 4; i++)
#pragma unroll
      for (int j = 0; j < NT; j++)
        acc1[i][j] = __builtin_amdgcn_mfma_f32_16x16x32_f16(aH[i], bH[j],
                                                            acc1[i][j], 0, 0, 0);
#pragma unroll
    for (int i = 0; i < 4; i++)
#pragma unroll
      for (int j = 0; j < NT; j++)
        acc2[i][j] = __builtin_amdgcn_mfma_f32_16x16x32_f16(aH[i], bL[j],
                                                            acc2[i][j], 0, 0, 0);
    __builtin_amdgcn_s_setprio(0);
#pragma unroll
    for (int t = 0; t < 4; t++)
      aL[t] = *(const f16x8*)&buf[sub * 4096 + (4 + t) * 512 + lane * 8];
    __builtin_amdgcn_s_setprio(1);
#pragma unroll
    for (int i = 0; i < 4; i++)
#pragma unroll
      for (int j = 0; j < NT; j++)
        acc2[i][j] = __builtin_amdgcn_mfma_f32_16x16x32_f16(aL[i], bH[j],
                                                            acc2[i][j], 0, 0, 0);
    __builtin_amdgcn_s_setprio(0);
  };

#define SB0 __builtin_amdgcn_sched_barrier(0)
#define WAIT_STAGE()                                              \
  do {                                                            \
    if constexpr (NT == 2)                                        \
      asm volatile("s_waitcnt vmcnt(4)" ::: "memory");            \
    else                                                          \
      asm volatile("s_waitcnt vmcnt(2)" ::: "memory");            \
  } while (0)

  // ---- prologue: stage window 0 -> lds0; load B(0); publish lds0.
  stageNext(lds0);                   // S0: 4  (FIFO-oldest)
  loadBNext(b0H, b0L);               // L(k0): 2NT
  WAIT_STAGE();                      // retires S0; L(k0) stays in flight
  __builtin_amdgcn_s_barrier();
  SB0;
  // invariant entering window w: outstanding [L(k0) 2NT]; buf[w] published

  short* cur = lds0;
  short* oth = lds1;
  for (int w = 0; w < W - 1; ++w) {
    loadBNext(b1H, b1L);             // L(k1): 2NT
    stageNext(oth);                  // S(w+1): 4 (other buffer; its reads
                                     // retired before last barrier)
    computeSub(cur, 0, b0H, b0L);    // auto-wait retires L(k0)
    SB0;                             // pin: S issued before L(k2)
    loadBNext(b0H, b0L);             // L(k2): 2NT
    computeSub(cur, 1, b1H, b1L);    // auto-wait retires L(k1)
    SB0;
    WAIT_STAGE();                    // retires S(w+1); L(k2) crosses
    __builtin_amdgcn_s_barrier();    // publish buf[w+1]
    SB0;
    short* t = cur; cur = oth; oth = t;
  }

  // ---- tail window W-1: no stage, no L(k2); compiler auto-waits.
  loadBNext(b1H, b1L);
  computeSub(cur, 0, b0H, b0L);
  computeSub(cur, 1, b1H, b1L);

  // epilogue: combine accs, bias + per-column activation + clip.
  // C/D map col=lane&15, row=quad*4+reg (m89-verified).
  // OUT_F16 path writes PACKED layout (next layer's A): chunkrow=row>>4,
  // kstep=col>>5, lane'=((col>>3)&3)*16 + (row&15), j'=col&7.
#pragma unroll
  for (int j = 0; j < NT; j++) {
    int col = blockN + wave * (NT * 16) + j * 16 + m16;
    float b = bias[col];
    float m = mo[col];
    int a = aid[col];
    size_t kbase = OUT_F16 ? ((size_t)(col >> 5) * MCH) * 512 +
                                 (size_t)((col >> 3) & 3) * 128 + (col & 7)
                           : 0;
#pragma unroll
    for (int i = 0; i < 4; i++) {
#pragma unroll
      for (int r = 0; r < 4; r++) {
        int row = blockM + i * 16 + quad * 4 + r;
        float s = acc1[i][j][r] + acc2[i][j][r] * INV_LO_SCALE;
        float v = rand_act(s + b, a, m);
        if (OUT_F16) {
          unsigned short h, l;
          split_h(v, h, l);
          size_t pidx = kbase + (size_t)(row >> 4) * 512 + (row & 15) * 8;
          Ch[pidx] = h;
          Cl[pidx] = l;
        } else {
          Cf[(size_t)row * N + col] = v;
        }
      }
    }
  }
}

extern "C" void kernel_launch(void* const* d_in, const int* in_sizes, int n_in,
                              void* d_out, int out_size, void* d_ws,
                              size_t ws_size, hipStream_t stream) {
  (void)in_sizes; (void)n_in; (void)out_size; (void)ws_size;

  const float* x     = (const float*)d_in[0];
  const float* W_in  = (const float*)d_in[1];
  const float* b_in  = (const float*)d_in[2];
  const float* Wh[6] = {(const float*)d_in[3], (const float*)d_in[4],
                        (const float*)d_in[5], (const float*)d_in[6],
                        (const float*)d_in[7], (const float*)d_in[8]};
  const float* bh    = (const float*)d_in[9];
  const float* W_out = (const float*)d_in[10];
  const float* b_out = (const float*)d_in[11];
  const float* mo_in = (const float*)d_in[12];
  const float* mo_h  = (const float*)d_in[13];
  const float* mo_out= (const float*)d_in[14];
  const int* aid_in  = (const int*)d_in[15];
  const int* aid_h   = (const int*)d_in[16];
  const int* aid_out = (const int*)d_in[17];

  const int hin[6] = {XDIM, XDIM, 2 * XDIM, XDIM, 2 * XDIM, XDIM};

  // workspace layout (~264 MB); each tensor = hi plane then lo plane (packed)
  char* p = (char*)d_ws;
  auto take = [&](size_t elems) {
    short* q = (short*)p;
    p += elems * 2 * 2;  // hi + lo, 2B each
    return q;
  };
  short* x_s = take((size_t)BDIM * INDIM);
  size_t xpl = (size_t)BDIM * INDIM;
  short* w_in_s = take((size_t)XDIM * INDIM);
  size_t wpl_in = (size_t)XDIM * INDIM;
  short* w_h_s[6];
  size_t wpl_h[6];
  for (int i = 0; i < 6; i++) {
    wpl_h[i] = (size_t)XDIM * hin[i];
    w_h_s[i] = take(wpl_h[i]);
  }
  short* w_out_s = take((size_t)OUTDIM * XDIM);
  size_t wpl_out = (size_t)OUTDIM * XDIM;
  const size_t apl = (size_t)BDIM * XDIM;  // activation plane
  short* actA = take(apl);
  short* actB = take(apl);
  short* actC = take(apl);

  // 1) pack x -> hi/lo fp16 packed
  pack_x<<<dim3(INDIM / 32, BDIM / 64), dim3(256), 0, stream>>>(
      x, (unsigned short*)x_s, (unsigned short*)(x_s + xpl), INDIM);
  // 2) pack all weights: W(K,N) -> packed BT(rows=N, Kdim=K) hi/lo
  pack_w<<<dim3(XDIM / 32, INDIM / 32), dim3(32, 8), 0, stream>>>(
      W_in, (unsigned short*)w_in_s, (unsigned short*)(w_in_s + wpl_in), INDIM,
      XDIM);
  for (int i = 0; i < 6; i++)
    pack_w<<<dim3(XDIM / 32, hin[i] / 32), dim3(32, 8), 0, stream>>>(
        Wh[i], (unsigned short*)w_h_s[i],
        (unsigned short*)(w_h_s[i] + wpl_h[i]), hin[i], XDIM);
  pack_w<<<dim3(OUTDIM / 32, XDIM / 32), dim3(32, 8), 0, stream>>>(
      W_out, (unsigned short*)w_out_s, (unsigned short*)(w_out_s + wpl_out),
      XDIM, OUTDIM);

  // 3) GEMM chain with 3 rotating activation buffers (all NT=2, N=2048)
  auto G = [&](const short* A1, size_t a1pl, const short* A2, size_t a2pl,
               const short* W, size_t wpl, const float* bi, const float* m,
               const int* a, short* Cb, int K, int Ks) {
    dim3 grid(XDIM / 128, BDIM / 64);
    const short* A2h = A2;
    const short* A2l = A2 ? A2 + a2pl : nullptr;
    gemm_split_act<true, 2><<<grid, 256, 0, stream>>>(
        A1, A1 + a1pl, A2h, A2l, W, W + wpl, bi, m, a, (unsigned short*)Cb,
        (unsigned short*)(Cb + apl), nullptr, XDIM, K, Ks);
  };

  // input layer: outs[0]=actA
  G(x_s, xpl, nullptr, 0, w_in_s, wpl_in, b_in, mo_in, aid_in, actA,
    INDIM, INDIM);
  // L0: outs[1]=actB
  G(actA, apl, nullptr, 0, w_h_s[0], wpl_h[0], bh + 0 * XDIM, mo_h + 0 * XDIM,
    aid_h + 0 * XDIM, actB, XDIM, XDIM);
  // L1: outs[2]=actC
  G(actB, apl, nullptr, 0, w_h_s[1], wpl_h[1], bh + 1 * XDIM, mo_h + 1 * XDIM,
    aid_h + 1 * XDIM, actC, XDIM, XDIM);
  // L2 (concat outs2,outs1): outs[3]=actA
  G(actC, apl, actB, apl, w_h_s[2], wpl_h[2], bh + 2 * XDIM, mo_h + 2 * XDIM,
    aid_h + 2 * XDIM, actA, 2 * XDIM, XDIM);
  // L3: outs[4]=actB
  G(actA, apl, nullptr, 0, w_h_s[3], wpl_h[3], bh + 3 * XDIM, mo_h + 3 * XDIM,
    aid_h + 3 * XDIM, actB, XDIM, XDIM);
  // L4 (concat outs4,outs3): outs[5]=actC
  G(actB, apl, actA, apl, w_h_s[4], wpl_h[4], bh + 4 * XDIM, mo_h + 4 * XDIM,
    aid_h + 4 * XDIM, actC, 2 * XDIM, XDIM);
  // L5: outs[6]=actB
  G(actC, apl, nullptr, 0, w_h_s[5], wpl_h[5], bh + 5 * XDIM, mo_h + 5 * XDIM,
    aid_h + 5 * XDIM, actB, XDIM, XDIM);
  // output layer -> d_out (fp32, row-major): N=512 -> NT=1, 64-wide tiles,
  // grid (8,64)=512 blocks = 2 blocks/CU.
  {
    dim3 grid(OUTDIM / 64, BDIM / 64);
    gemm_split_act<false, 1><<<grid, 256, 0, stream>>>(
        actB, actB + apl, nullptr, nullptr, w_out_s, w_out_s + wpl_out, b_out,
        mo_out, aid_out, nullptr, nullptr, (float*)d_out, OUTDIM, XDIM, XDIM);
  }
}

// Round 10
// 1087.872 us; speedup vs baseline: 5.3625x; 1.0002x over previous
//
#include <hip/hip_runtime.h>
#include <stdint.h>
#include <string.h>

// Problem dims (fixed by the reference)
#define BDIM   4096
#define INDIM  1024
#define XDIM   2048
#define OUTDIM 512
#define MCH    (BDIM / 16)   // 256 row-chunks along M for packed activations

#define LO_SCALE 2048.0f         // 2^11: lifts fp16 lo-plane out of subnormals
#define INV_LO_SCALE (1.0f / 2048.0f)

typedef _Float16 f16x8 __attribute__((ext_vector_type(8)));
typedef float f32x4 __attribute__((ext_vector_type(4)));
typedef unsigned short u16x8 __attribute__((ext_vector_type(8)));
typedef unsigned short u16x4 __attribute__((ext_vector_type(4)));

__device__ __forceinline__ unsigned short h2u(_Float16 h) {
  unsigned short u;
  memcpy(&u, &h, 2);
  return u;
}

// split f32 into hi fp16 + scaled-lo fp16 (combined ~22 mantissa bits)
__device__ __forceinline__ void split_h(float v, unsigned short& h,
                                        unsigned short& l) {
  _Float16 hh = (_Float16)v;                       // RTNE
  float r = v - (float)hh;                         // exact
  _Float16 ll = (_Float16)(r * LO_SCALE);          // |r|*2^11 <= |v|, no inf
  h = h2u(hh);
  l = h2u(ll);
}

// async global->LDS, 16B per lane; LDS dest wave-uniform base + lane*16
__device__ __forceinline__ void gld_lds16(const void* g, void* l) {
  __builtin_amdgcn_global_load_lds(
      (const __attribute__((address_space(1))) uint32_t*)g,
      (__attribute__((address_space(3))) uint32_t*)l, 16, 0, 0);
}

// fused RandomActivation + clip (relu/sigmoid/tanh/leaky(.1)/selu), libm-grade
__device__ __forceinline__ float rand_act(float v, int a, float mo) {
  float r;
  if (a == 0) {
    r = fmaxf(v, 0.0f);
  } else if (a == 1) {
    r = 1.0f / (1.0f + expf(-v));
  } else if (a == 2) {
    r = tanhf(v);
  } else if (a == 3) {
    r = (v >= 0.0f) ? v : 0.1f * v;
  } else {  // selu (matches jax: scale * where(v>0, v, alpha*expm1(v)))
    r = (v > 0.0f) ? 1.0507009873554805f * v
                   : 1.7580993408473766f * expm1f(v);
  }
  return fminf(r, mo);
}

// ---------------------------------------------------------------------------
// PACKED LAYOUT: tensor X[rows][K] is stored as
//   packed[k/32][row/16][lane(64)][8 halfs],
// lane = quad*16 + m16 holding X[chunkrow*16 + m16][kstep*32 + quad*8 + j].
// Each (kstep,chunk) = contiguous 1 KB: staging DMA is consecutive-lane-
// contiguous AND compute ds_read_b128 is contiguous (zero conflicts).
// Concat along K = packed tensors back-to-back.
// ---------------------------------------------------------------------------

// x[BDIM][Kin] f32 row-major -> packed hi/lo planes. grid(Kin/32, BDIM/64)x256
__global__ void pack_x(const float* __restrict__ s,
                       unsigned short* __restrict__ dh,
                       unsigned short* __restrict__ dl, int Kin) {
  int ks = blockIdx.x;
  int mblk = blockIdx.y;
  int cc = threadIdx.x >> 6;        // chunk within 64-row group
  int lane = threadIdx.x & 63;
  int m16 = lane & 15, quad = lane >> 4;
  int row = mblk * 64 + cc * 16 + m16;
  const float* src = s + (size_t)row * Kin + ks * 32 + quad * 8;
  size_t o = ((size_t)ks * MCH + mblk * 4 + cc) * 512 + lane * 8;
  float4 v0 = *(const float4*)src;
  float4 v1 = *(const float4*)(src + 4);
  float vs[8] = {v0.x, v0.y, v0.z, v0.w, v1.x, v1.y, v1.z, v1.w};
  u16x8 vh, vl;
#pragma unroll
  for (int j = 0; j < 8; j++) {
    unsigned short h, l;
    split_h(vs[j], h, l);
    vh[j] = h;
    vl[j] = l;
  }
  *(u16x8*)(dh + o) = vh;
  *(u16x8*)(dl + o) = vl;
}

// W[K][N] f32 row-major -> packed-BT hi/lo (rows=N, Kdim=K).
// grid(N/32, K/32), block(32,8).
__global__ void pack_w(const float* __restrict__ W,
                       unsigned short* __restrict__ dh,
                       unsigned short* __restrict__ dl, int K, int N) {
  __shared__ float t[32][33];       // t[k'][n']
  int n0 = blockIdx.x * 32, k0 = blockIdx.y * 32;
  int tx = threadIdx.x, ty = threadIdx.y;
#pragma unroll
  for (int i = 0; i < 32; i += 8)
    t[ty + i][tx] = W[(size_t)(k0 + ty + i) * N + n0 + tx];
  __syncthreads();
  int tt = ty * 32 + tx;            // 0..255
  int ci = tt >> 7;                 // n-chunk 0/1
  int rem = tt & 127;
  int lane = rem >> 1;
  int j4 = (rem & 1) * 4;
  int m16 = lane & 15, quad = lane >> 4;
  size_t o = ((size_t)(k0 >> 5) * (N >> 4) + (n0 >> 4) + ci) * 512 +
             lane * 8 + j4;
  u16x4 vh, vl;
#pragma unroll
  for (int jj = 0; jj < 4; jj++) {
    float v = t[quad * 8 + j4 + jj][ci * 16 + m16];
    unsigned short h, l;
    split_h(v, h, l);
    vh[jj] = h;
    vl[jj] = l;
  }
  *(u16x4*)(dh + o) = vh;
  *(u16x4*)(dl + o) = vl;
}

// C[M,N] = act( A[M,K] @ BT[N,K]^T + bias ), split-fp16 (3-term) precision.
// acc1 = hi*hi; acc2 = hi*lo' + lo'*hi at scale 2^11. Final = acc1+acc2/2^11.
//
// Round-19 = Round-7/9 structure (verified twice: 194.5-196.0 us hot,
// 1088-1116 us total) generalized with an MT (M-tiles per wave) parameter:
//  - MT=4, NT=2: block 64x128 — all N=2048 layers (code identical to R9).
//  - MT=4, NT=1: (retired) was the out layer at 2 blocks/CU.
//  - MT=2, NT=1: block 32x64 for the OUTPUT layer (N=512): grid (8,128) =
//    1024 blocks = 4 blocks/CU = 4 waves/SIMD (the R2/R4-proven TLP
//    requirement; at 64-row tiles this layer could only reach 2 waves/SIMD).
//  - counted-vmcnt single-barrier window (2 K-steps), 2 LDS buffers of
//    2*MT KB; ledger: stage = MT DMAs/wave/window, loadB = 2NT/K-step;
//    pre-barrier vmcnt(2NT) retires exactly the stage; never drains to 0.
//  - arch VGPR <= 64 (unified file: AGPR acc + arch <= 128 -> 4 waves/SIMD).
//  - linear block order (R1: XCD swizzle +70% FETCH — refuted).
//  - 16x16x32 MFMA (R6: 32x32x16 −26% at this wave count — refuted).
template <bool OUT_F16, int NT, int MT>
__global__ __launch_bounds__(256, 4) void gemm_split_act(
    const short* __restrict__ A1h, const short* __restrict__ A1l,
    const short* __restrict__ A2h, const short* __restrict__ A2l,
    const short* __restrict__ BTh, const short* __restrict__ BTl,
    const float* __restrict__ bias, const float* __restrict__ mo,
    const int* __restrict__ aid, unsigned short* __restrict__ Ch,
    unsigned short* __restrict__ Cl, float* __restrict__ Cf, int N, int K,
    int Ksplit) {
  constexpr int CH = 2 * MT;             // chunks per K-sub-step (hi MT + lo MT)
  __shared__ short lds0[2 * CH * 512];   // [sub][CH chunks][512]
  __shared__ short lds1[2 * CH * 512];

  const int tid = threadIdx.x;
  const int lane = tid & 63;
  const int wave = tid >> 6;        // 0..3 = n-strip of wave
  const int m16 = lane & 15, quad = lane >> 4;

  const int blockN = blockIdx.x * (NT * 64);  // linear order (proven)
  const int blockM = blockIdx.y * (MT * 16);

  f32x4 acc1[MT][NT];  // hi*hi
  f32x4 acc2[MT][NT];  // (hi*lo' + lo'*hi), scale 2^11
#pragma unroll
  for (int i = 0; i < MT; i++)
#pragma unroll
    for (int j = 0; j < NT; j++) {
      acc1[i][j] = (f32x4){0.f, 0.f, 0.f, 0.f};
      acc2[i][j] = (f32x4){0.f, 0.f, 0.f, 0.f};
    }

  const int KSTEPS = K >> 5;        // 32/64/128 — always even, >= 32
  const int W = KSTEPS >> 1;        // windows (16/32/64)
  const int KS1W = (Ksplit >> 5) >> 1;  // part-1 windows (even splits only)

  // ---- staging: one window = 2 k-steps = MT DMAs/wave (1 KB each)
  const short* sAh = A1h;
  const short* sAl = A1l;
  const unsigned aBase0 = (unsigned)((blockM >> 4) * 512 + lane * 8);
  unsigned aOff = aBase0;
  int stageW = 0;
  auto stageNext = [&](short* dst) {
#pragma unroll
    for (int sub = 0; sub < 2; sub++) {
#pragma unroll
      for (int s = 0; s < MT / 2; s++) {
        int g = wave * (MT / 2) + s;   // 0..CH-1
        const short* plane = (g < MT) ? sAh : sAl;
        gld_lds16(plane + aOff + sub * (MCH * 512) + (g & (MT - 1)) * 512,
                  dst + sub * (CH * 512) + g * 512);
      }
    }
    aOff += 2u * (MCH * 512);
    if (++stageW == KS1W) { sAh = A2h; sAl = A2l; aOff = aBase0; }
  };

  // ---- B-load state (2*NT x 16B loads per wave per K-step), 32-bit offset
  unsigned bOff = (unsigned)(((blockN >> 4) + wave * NT) * 512 + lane * 8);
  const unsigned bStride = (unsigned)N * 32;
  auto loadBNext = [&](f16x8 (&bH)[NT], f16x8 (&bL)[NT]) {
#pragma unroll
    for (int t = 0; t < NT; t++) {
      bH[t] = *(const f16x8*)(BTh + bOff + t * 512);
      bL[t] = *(const f16x8*)(BTl + bOff + t * 512);
    }
    bOff += bStride;
  };

  f16x8 aH[MT], aL[MT];             // single A-frag set
  f16x8 b0H[NT], b0L[NT], b1H[NT], b1L[NT];

  // one K-sub-step: aH reads -> 2*MT*NT MFMA -> aL reads -> MT*NT MFMA
  // (staggered liveness keeps arch VGPR <= 64)
  auto computeSub = [&](const short* buf, int sub, f16x8 (&bH)[NT],
                        f16x8 (&bL)[NT]) {
#pragma unroll
    for (int t = 0; t < MT; t++)
      aH[t] = *(const f16x8*)&buf[sub * (CH * 512) + t * 512 + lane * 8];
    __builtin_amdgcn_s_setprio(1);
#pragma unroll
    for (int i = 0; i < MT; i++)
#pragma unroll
      for (int j = 0; j < NT; j++)
        acc1[i][j] = __builtin_amdgcn_mfma_f32_16x16x32_f16(aH[i], bH[j],
                                                            acc1[i][j], 0, 0, 0);
#pragma unroll
    for (int i = 0; i < MT; i++)
#pragma unroll
      for (int j = 0; j < NT; j++)
        acc2[i][j] = __builtin_amdgcn_mfma_f32_16x16x32_f16(aH[i], bL[j],
                                                            acc2[i][j], 0, 0, 0);
    __builtin_amdgcn_s_setprio(0);
#pragma unroll
    for (int t = 0; t < MT; t++)
      aL[t] = *(const f16x8*)&buf[sub * (CH * 512) + (MT + t) * 512 +
                                  lane * 8];
    __builtin_amdgcn_s_setprio(1);
#pragma unroll
    for (int i = 0; i < MT; i++)
#pragma unroll
      for (int j = 0; j < NT; j++)
        acc2[i][j] = __builtin_amdgcn_mfma_f32_16x16x32_f16(aL[i], bH[j],
                                                            acc2[i][j], 0, 0, 0);
    __builtin_amdgcn_s_setprio(0);
  };

#define SB0 __builtin_amdgcn_sched_barrier(0)
#define WAIT_STAGE()                                              \
  do {                                                            \
    if constexpr (NT == 2)                                        \
      asm volatile("s_waitcnt vmcnt(4)" ::: "memory");            \
    else                                                          \
      asm volatile("s_waitcnt vmcnt(2)" ::: "memory");            \
  } while (0)

  // ---- prologue: stage window 0 -> lds0; load B(0); publish lds0.
  stageNext(lds0);                   // S0: MT  (FIFO-oldest)
  loadBNext(b0H, b0L);               // L(k0): 2NT
  WAIT_STAGE();                      // retires S0; L(k0) stays in flight
  __builtin_amdgcn_s_barrier();
  SB0;
  // invariant entering window w: outstanding [L(k0) 2NT]; buf[w] published

  short* cur = lds0;
  short* oth = lds1;
  for (int w = 0; w < W - 1; ++w) {
    loadBNext(b1H, b1L);             // L(k1): 2NT
    stageNext(oth);                  // S(w+1): MT (other buffer; its reads
                                     // retired before last barrier)
    computeSub(cur, 0, b0H, b0L);    // auto-wait retires L(k0)
    SB0;                             // pin: S issued before L(k2)
    loadBNext(b0H, b0L);             // L(k2): 2NT
    computeSub(cur, 1, b1H, b1L);    // auto-wait retires L(k1)
    SB0;
    WAIT_STAGE();                    // retires S(w+1); L(k2) crosses
    __builtin_amdgcn_s_barrier();    // publish buf[w+1]
    SB0;
    short* t = cur; cur = oth; oth = t;
  }

  // ---- tail window W-1: no stage, no L(k2); compiler auto-waits.
  loadBNext(b1H, b1L);
  computeSub(cur, 0, b0H, b0L);
  computeSub(cur, 1, b1H, b1L);

  // epilogue: combine accs, bias + per-column activation + clip.
  // C/D map col=lane&15, row=quad*4+reg (m89-verified).
  // OUT_F16 path writes PACKED layout (next layer's A): chunkrow=row>>4,
  // kstep=col>>5, lane'=((col>>3)&3)*16 + (row&15), j'=col&7.
#pragma unroll
  for (int j = 0; j < NT; j++) {
    int col = blockN + wave * (NT * 16) + j * 16 + m16;
    float b = bias[col];
    float m = mo[col];
    int a = aid[col];
    size_t kbase = OUT_F16 ? ((size_t)(col >> 5) * MCH) * 512 +
                                 (size_t)((col >> 3) & 3) * 128 + (col & 7)
                           : 0;
#pragma unroll
    for (int i = 0; i < MT; i++) {
#pragma unroll
      for (int r = 0; r < 4; r++) {
        int row = blockM + i * 16 + quad * 4 + r;
        float s = acc1[i][j][r] + acc2[i][j][r] * INV_LO_SCALE;
        float v = rand_act(s + b, a, m);
        if (OUT_F16) {
          unsigned short h, l;
          split_h(v, h, l);
          size_t pidx = kbase + (size_t)(row >> 4) * 512 + (row & 15) * 8;
          Ch[pidx] = h;
          Cl[pidx] = l;
        } else {
          Cf[(size_t)row * N + col] = v;
        }
      }
    }
  }
}

extern "C" void kernel_launch(void* const* d_in, const int* in_sizes, int n_in,
                              void* d_out, int out_size, void* d_ws,
                              size_t ws_size, hipStream_t stream) {
  (void)in_sizes; (void)n_in; (void)out_size; (void)ws_size;

  const float* x     = (const float*)d_in[0];
  const float* W_in  = (const float*)d_in[1];
  const float* b_in  = (const float*)d_in[2];
  const float* Wh[6] = {(const float*)d_in[3], (const float*)d_in[4],
                        (const float*)d_in[5], (const float*)d_in[6],
                        (const float*)d_in[7], (const float*)d_in[8]};
  const float* bh    = (const float*)d_in[9];
  const float* W_out = (const float*)d_in[10];
  const float* b_out = (const float*)d_in[11];
  const float* mo_in = (const float*)d_in[12];
  const float* mo_h  = (const float*)d_in[13];
  const float* mo_out= (const float*)d_in[14];
  const int* aid_in  = (const int*)d_in[15];
  const int* aid_h   = (const int*)d_in[16];
  const int* aid_out = (const int*)d_in[17];

  const int hin[6] = {XDIM, XDIM, 2 * XDIM, XDIM, 2 * XDIM, XDIM};

  // workspace layout (~264 MB); each tensor = hi plane then lo plane (packed)
  char* p = (char*)d_ws;
  auto take = [&](size_t elems) {
    short* q = (short*)p;
    p += elems * 2 * 2;  // hi + lo, 2B each
    return q;
  };
  short* x_s = take((size_t)BDIM * INDIM);
  size_t xpl = (size_t)BDIM * INDIM;
  short* w_in_s = take((size_t)XDIM * INDIM);
  size_t wpl_in = (size_t)XDIM * INDIM;
  short* w_h_s[6];
  size_t wpl_h[6];
  for (int i = 0; i < 6; i++) {
    wpl_h[i] = (size_t)XDIM * hin[i];
    w_h_s[i] = take(wpl_h[i]);
  }
  short* w_out_s = take((size_t)OUTDIM * XDIM);
  size_t wpl_out = (size_t)OUTDIM * XDIM;
  const size_t apl = (size_t)BDIM * XDIM;  // activation plane
  short* actA = take(apl);
  short* actB = take(apl);
  short* actC = take(apl);

  // 1) pack x -> hi/lo fp16 packed
  pack_x<<<dim3(INDIM / 32, BDIM / 64), dim3(256), 0, stream>>>(
      x, (unsigned short*)x_s, (unsigned short*)(x_s + xpl), INDIM);
  // 2) pack all weights: W(K,N) -> packed BT(rows=N, Kdim=K) hi/lo
  pack_w<<<dim3(XDIM / 32, INDIM / 32), dim3(32, 8), 0, stream>>>(
      W_in, (unsigned short*)w_in_s, (unsigned short*)(w_in_s + wpl_in), INDIM,
      XDIM);
  for (int i = 0; i < 6; i++)
    pack_w<<<dim3(XDIM / 32, hin[i] / 32), dim3(32, 8), 0, stream>>>(
        Wh[i], (unsigned short*)w_h_s[i],
        (unsigned short*)(w_h_s[i] + wpl_h[i]), hin[i], XDIM);
  pack_w<<<dim3(OUTDIM / 32, XDIM / 32), dim3(32, 8), 0, stream>>>(
      W_out, (unsigned short*)w_out_s, (unsigned short*)(w_out_s + wpl_out),
      XDIM, OUTDIM);

  // 3) GEMM chain with 3 rotating activation buffers (all MT=4/NT=2, N=2048)
  auto G = [&](const short* A1, size_t a1pl, const short* A2, size_t a2pl,
               const short* W, size_t wpl, const float* bi, const float* m,
               const int* a, short* Cb, int K, int Ks) {
    dim3 grid(XDIM / 128, BDIM / 64);
    const short* A2h = A2;
    const short* A2l = A2 ? A2 + a2pl : nullptr;
    gemm_split_act<true, 2, 4><<<grid, 256, 0, stream>>>(
        A1, A1 + a1pl, A2h, A2l, W, W + wpl, bi, m, a, (unsigned short*)Cb,
        (unsigned short*)(Cb + apl), nullptr, XDIM, K, Ks);
  };

  // input layer: outs[0]=actA
  G(x_s, xpl, nullptr, 0, w_in_s, wpl_in, b_in, mo_in, aid_in, actA,
    INDIM, INDIM);
  // L0: outs[1]=actB
  G(actA, apl, nullptr, 0, w_h_s[0], wpl_h[0], bh + 0 * XDIM, mo_h + 0 * XDIM,
    aid_h + 0 * XDIM, actB, XDIM, XDIM);
  // L1: outs[2]=actC
  G(actB, apl, nullptr, 0, w_h_s[1], wpl_h[1], bh + 1 * XDIM, mo_h + 1 * XDIM,
    aid_h + 1 * XDIM, actC, XDIM, XDIM);
  // L2 (concat outs2,outs1): outs[3]=actA
  G(actC, apl, actB, apl, w_h_s[2], wpl_h[2], bh + 2 * XDIM, mo_h + 2 * XDIM,
    aid_h + 2 * XDIM, actA, 2 * XDIM, XDIM);
  // L3: outs[4]=actB
  G(actA, apl, nullptr, 0, w_h_s[3], wpl_h[3], bh + 3 * XDIM, mo_h + 3 * XDIM,
    aid_h + 3 * XDIM, actB, XDIM, XDIM);
  // L4 (concat outs4,outs3): outs[5]=actC
  G(actB, apl, actA, apl, w_h_s[4], wpl_h[4], bh + 4 * XDIM, mo_h + 4 * XDIM,
    aid_h + 4 * XDIM, actC, 2 * XDIM, XDIM);
  // L5: outs[6]=actB
  G(actC, apl, nullptr, 0, w_h_s[5], wpl_h[5], bh + 5 * XDIM, mo_h + 5 * XDIM,
    aid_h + 5 * XDIM, actB, XDIM, XDIM);
  // output layer -> d_out (fp32, row-major): N=512 -> MT=2/NT=1 (32x64
  // tiles): grid (8,128) = 1024 blocks = 4 blocks/CU = 4 waves/SIMD
  // (was 512 blocks = 2/CU = 2 waves/SIMD, the R4-proven ~20% penalty class).
  {
    dim3 grid(OUTDIM / 64, BDIM / 32);
    gemm_split_act<false, 1, 2><<<grid, 256, 0, stream>>>(
        actB, actB + apl, nullptr, nullptr, w_out_s, w_out_s + wpl_out, b_out,
        mo_out, aid_out, nullptr, nullptr, (float*)d_out, OUTDIM, XDIM, XDIM);
  }
}